// Round 1
// baseline (1788.166 us; speedup 1.0000x reference)
//
#include <hip/hip_runtime.h>
#include <math.h>

#define LL 1024
#define DD 512
#define NBATCH 16

static const long NLD = (long)NBATCH * LL * DD; // 8,388,608

// ---------------------------------------------------------------------------
// Tiled fp32 GEMM core: C_tile(64x64) += A(64xK) * B, BK=16, 256 threads,
// each thread computes a 4x4 micro-tile.
// BT=true : B is row-major [N][K]  (NT gemm, k is inner dim of both operands)
// BT=false: B is row-major [K][N]  (NN gemm)
// ---------------------------------------------------------------------------
template <bool BT>
__device__ __forceinline__ void gemm_core(const float* __restrict__ A, int lda,
                                          const float* __restrict__ B, int ldb,
                                          int K, int bm, int bn,
                                          float acc[4][4]) {
  __shared__ float As[16][68];
  __shared__ float Bs[16][68];

  const int tid = threadIdx.x;          // 0..255
  const int tx = tid & 15;
  const int ty = tid >> 4;
  const int arow = tid >> 2;            // 0..63
  const int akc = (tid & 3) * 4;        // 0,4,8,12

  const float* Ag = A + (long)(bm + arow) * lda + akc;
  const float* Bg;
  if constexpr (BT) {
    Bg = B + (long)(bn + arow) * ldb + akc;
  } else {
    Bg = B + (long)(tid >> 4) * ldb + bn + (tid & 15) * 4;
  }

  for (int k0 = 0; k0 < K; k0 += 16) {
    float4 av = *(const float4*)(Ag + k0);
    As[akc + 0][arow] = av.x;
    As[akc + 1][arow] = av.y;
    As[akc + 2][arow] = av.z;
    As[akc + 3][arow] = av.w;
    if constexpr (BT) {
      float4 bv = *(const float4*)(Bg + k0);
      Bs[akc + 0][arow] = bv.x;
      Bs[akc + 1][arow] = bv.y;
      Bs[akc + 2][arow] = bv.z;
      Bs[akc + 3][arow] = bv.w;
    } else {
      float4 bv = *(const float4*)(Bg + (long)k0 * ldb);
      *(float4*)&Bs[tid >> 4][(tid & 15) * 4] = bv;
    }
    __syncthreads();
#pragma unroll
    for (int kk = 0; kk < 16; ++kk) {
      float4 a4 = *(const float4*)&As[kk][ty * 4];
      float4 b4 = *(const float4*)&Bs[kk][tx * 4];
      float aa[4] = {a4.x, a4.y, a4.z, a4.w};
      float bb[4] = {b4.x, b4.y, b4.z, b4.w};
#pragma unroll
      for (int i = 0; i < 4; ++i)
#pragma unroll
        for (int j = 0; j < 4; ++j) acc[i][j] = fmaf(aa[i], bb[j], acc[i][j]);
    }
    __syncthreads();
  }
}

// ---------------------------------------------------------------------------
// 5 projections: C[n,e] = sum_d X[n,d] * W[e,d]   (M=16384, N=K=512, NT)
// z: 0 qp=q*Wq  1 kp=k*Wk  2 vp=v*Wv  3 qt0=q*Wqt  4 kt0=k*Wkt
// ---------------------------------------------------------------------------
__global__ __launch_bounds__(256) void k_proj(
    const float* __restrict__ q, const float* __restrict__ k,
    const float* __restrict__ v, const float* __restrict__ Wq,
    const float* __restrict__ Wk, const float* __restrict__ Wv,
    const float* __restrict__ Wqt, const float* __restrict__ Wkt,
    float* __restrict__ qp, float* __restrict__ kp, float* __restrict__ vp,
    float* __restrict__ qt0, float* __restrict__ kt0) {
  const float *A, *B;
  float* C;
  switch (blockIdx.z) {
    case 0: A = q; B = Wq; C = qp; break;
    case 1: A = k; B = Wk; C = kp; break;
    case 2: A = v; B = Wv; C = vp; break;
    case 3: A = q; B = Wqt; C = qt0; break;
    default: A = k; B = Wkt; C = kt0; break;
  }
  const int bm = blockIdx.y * 64, bn = blockIdx.x * 64;
  float acc[4][4] = {};
  gemm_core<true>(A, DD, B, DD, DD, bm, bn, acc);
  const int tx = threadIdx.x & 15, ty = threadIdx.x >> 4;
#pragma unroll
  for (int i = 0; i < 4; ++i) {
    float4 o = make_float4(acc[i][0], acc[i][1], acc[i][2], acc[i][3]);
    *(float4*)&C[(long)(bm + ty * 4 + i) * DD + bn + tx * 4] = o;
  }
}

// ---------------------------------------------------------------------------
// Distance matmuls: qt[b,l,d] = sum_m dist[b,l,m]*qt0[b,m,d]  (NN, K=1024)
// grid.z = b*2 + sel  (sel 0 -> qt, 1 -> kt)
// ---------------------------------------------------------------------------
__global__ __launch_bounds__(256) void k_dist(
    const float* __restrict__ dist, const float* __restrict__ qt0,
    const float* __restrict__ kt0, float* __restrict__ qt,
    float* __restrict__ kt) {
  const int b = blockIdx.z >> 1;
  const int sel = blockIdx.z & 1;
  const float* A = dist + (long)b * LL * LL;
  const float* B = (sel ? kt0 : qt0) + (long)b * LL * DD;
  float* C = (sel ? kt : qt) + (long)b * LL * DD;
  const int bm = blockIdx.y * 64, bn = blockIdx.x * 64;
  float acc[4][4] = {};
  gemm_core<false>(A, LL, B, DD, LL, bm, bn, acc);
  const int tx = threadIdx.x & 15, ty = threadIdx.x >> 4;
#pragma unroll
  for (int i = 0; i < 4; ++i) {
    float4 o = make_float4(acc[i][0], acc[i][1], acc[i][2], acc[i][3]);
    *(float4*)&C[(long)(bm + ty * 4 + i) * DD + bn + tx * 4] = o;
  }
}

// ---------------------------------------------------------------------------
// Attention scores: attn[b,l,m] = tanh((qp.kp + qt.kt)/temp) masked on m
// Two NT passes (K=512 each), then mask+tanh epilogue, write to d_out.
// ---------------------------------------------------------------------------
__global__ __launch_bounds__(256) void k_attn(
    const float* __restrict__ qp, const float* __restrict__ kp,
    const float* __restrict__ qt, const float* __restrict__ kt,
    const int* __restrict__ lens, float* __restrict__ attnO) {
  const int b = blockIdx.z;
  const long o = (long)b * LL * DD;
  const int bm = blockIdx.y * 64, bn = blockIdx.x * 64;
  float acc[4][4] = {};
  gemm_core<true>(qp + o, DD, kp + o, DD, DD, bm, bn, acc);
  gemm_core<true>(qt + o, DD, kt + o, DD, DD, bm, bn, acc);
  const int len = lens[b];
  const float invt = 0.04419417382415922f;  // 1/sqrt(512)
  const int tx = threadIdx.x & 15, ty = threadIdx.x >> 4;
#pragma unroll
  for (int i = 0; i < 4; ++i) {
    const int row = bm + ty * 4 + i;
    float4 o4;
    float* po = (float*)&o4;
#pragma unroll
    for (int j = 0; j < 4; ++j) {
      const int col = bn + tx * 4 + j;
      po[j] = (col < len) ? tanhf(acc[i][j] * invt) : 0.0f;
    }
    *(float4*)&attnO[(long)b * LL * LL + (long)row * LL + bn + tx * 4] = o4;
  }
}

// ---------------------------------------------------------------------------
// PV: out0[b,l,d] = sum_m attn[b,l,m]*vp[b,m,d]   (NN, K=1024)
// ---------------------------------------------------------------------------
__global__ __launch_bounds__(256) void k_pv(const float* __restrict__ attnO,
                                            const float* __restrict__ vp,
                                            float* __restrict__ out0) {
  const int b = blockIdx.z;
  const float* A = attnO + (long)b * LL * LL;
  const float* B = vp + (long)b * LL * DD;
  float* C = out0 + (long)b * LL * DD;
  const int bm = blockIdx.y * 64, bn = blockIdx.x * 64;
  float acc[4][4] = {};
  gemm_core<false>(A, LL, B, DD, LL, bm, bn, acc);
  const int tx = threadIdx.x & 15, ty = threadIdx.x >> 4;
#pragma unroll
  for (int i = 0; i < 4; ++i) {
    float4 o = make_float4(acc[i][0], acc[i][1], acc[i][2], acc[i][3]);
    *(float4*)&C[(long)(bm + ty * 4 + i) * DD + bn + tx * 4] = o;
  }
}

// ---------------------------------------------------------------------------
// FC + residual: out1[n,e] = sum_d out0[n,d]*Wfc[e,d] + q[n,e]  (NT)
// ---------------------------------------------------------------------------
__global__ __launch_bounds__(256) void k_fc(const float* __restrict__ out0,
                                            const float* __restrict__ Wfc,
                                            const float* __restrict__ q,
                                            float* __restrict__ out1) {
  const int bm = blockIdx.y * 64, bn = blockIdx.x * 64;
  float acc[4][4] = {};
  gemm_core<true>(out0, DD, Wfc, DD, DD, bm, bn, acc);
  const int tx = threadIdx.x & 15, ty = threadIdx.x >> 4;
#pragma unroll
  for (int i = 0; i < 4; ++i) {
    const long r = (long)(bm + ty * 4 + i) * DD + bn + tx * 4;
    float4 res = *(const float4*)&q[r];
    float4 o = make_float4(acc[i][0] + res.x, acc[i][1] + res.y,
                           acc[i][2] + res.z, acc[i][3] + res.w);
    *(float4*)&out1[r] = o;
  }
}

// ---------------------------------------------------------------------------
// LayerNorm over last dim (512), one block (256 thr) per row.
// ---------------------------------------------------------------------------
__global__ __launch_bounds__(256) void k_ln(const float* __restrict__ x,
                                            const float* __restrict__ gamma,
                                            const float* __restrict__ beta,
                                            float* __restrict__ y) {
  const int r = blockIdx.x;
  const float* xr = x + (long)r * DD;
  const int t = threadIdx.x;
  const float x0 = xr[t], x1 = xr[t + 256];
  float s1 = x0 + x1;
  float s2 = x0 * x0 + x1 * x1;
#pragma unroll
  for (int off = 32; off; off >>= 1) {
    s1 += __shfl_down(s1, off);
    s2 += __shfl_down(s2, off);
  }
  __shared__ float r1[4], r2[4];
  __shared__ float smu, srs;
  const int w = t >> 6;
  if ((t & 63) == 0) {
    r1[w] = s1;
    r2[w] = s2;
  }
  __syncthreads();
  if (t == 0) {
    const float t1 = r1[0] + r1[1] + r1[2] + r1[3];
    const float t2 = r2[0] + r2[1] + r2[2] + r2[3];
    const float mu = t1 / (float)DD;
    const float var = t2 / (float)DD - mu * mu;
    smu = mu;
    srs = rsqrtf(var + 1e-6f);
  }
  __syncthreads();
  const float mu = smu, rs = srs;
  y[(long)r * DD + t] = (x0 - mu) * rs * gamma[t] + beta[t];
  y[(long)r * DD + t + 256] = (x1 - mu) * rs * gamma[t + 256] + beta[t + 256];
}

// ---------------------------------------------------------------------------
extern "C" void kernel_launch(void* const* d_in, const int* in_sizes, int n_in,
                              void* d_out, int out_size, void* d_ws,
                              size_t ws_size, hipStream_t stream) {
  const float* q = (const float*)d_in[0];
  const float* k = (const float*)d_in[1];
  const float* v = (const float*)d_in[2];
  const int* lens = (const int*)d_in[3];
  const float* dist = (const float*)d_in[4];
  const float* Wq = (const float*)d_in[5];
  const float* Wk = (const float*)d_in[6];
  const float* Wv = (const float*)d_in[7];
  const float* Wqt = (const float*)d_in[8];
  const float* Wkt = (const float*)d_in[9];
  const float* Wfc = (const float*)d_in[10];
  const float* gamma = (const float*)d_in[11];
  const float* beta = (const float*)d_in[12];

  float* ws = (float*)d_ws;
  float* qp = ws + 0 * NLD;
  float* kp = ws + 1 * NLD;
  float* vp = ws + 2 * NLD;
  float* qt0 = ws + 3 * NLD;
  float* kt0 = ws + 4 * NLD;
  float* qt = ws + 5 * NLD;
  float* kt = ws + 6 * NLD;
  float* out0 = ws + 3 * NLD;  // reuse qt0 (dead after k_dist)
  float* out1 = ws + 4 * NLD;  // reuse kt0 (dead after k_dist)

  float* outO = (float*)d_out;
  float* attnO = outO + NLD;

  dim3 blk(256);
  k_proj<<<dim3(DD / 64, (NBATCH * LL) / 64, 5), blk, 0, stream>>>(
      q, k, v, Wq, Wk, Wv, Wqt, Wkt, qp, kp, vp, qt0, kt0);
  k_dist<<<dim3(DD / 64, LL / 64, NBATCH * 2), blk, 0, stream>>>(dist, qt0,
                                                                 kt0, qt, kt);
  k_attn<<<dim3(LL / 64, LL / 64, NBATCH), blk, 0, stream>>>(qp, kp, qt, kt,
                                                             lens, attnO);
  k_pv<<<dim3(DD / 64, LL / 64, NBATCH), blk, 0, stream>>>(attnO, vp, out0);
  k_fc<<<dim3(DD / 64, (NBATCH * LL) / 64, 1), blk, 0, stream>>>(out0, Wfc, q,
                                                                 out1);
  k_ln<<<NBATCH * LL, blk, 0, stream>>>(out1, gamma, beta, outO);
}

// Round 2
// 538.435 us; speedup vs baseline: 3.3210x; 3.3210x over previous
//
#include <hip/hip_runtime.h>
#include <math.h>

#define LL 1024
#define DD 512
#define NB 16
#define BK 32

typedef __attribute__((ext_vector_type(8))) short bf16x8;
typedef __attribute__((ext_vector_type(4))) float f32x4;
typedef unsigned short u16;
typedef unsigned int u32;
typedef const __attribute__((address_space(1))) void* gptr_t;
typedef __attribute__((address_space(3))) void* sptr_t;

static const long NLD = (long)NB * LL * DD;  // 8,388,608
static const long NLL = (long)NB * LL * LL;  // 16,777,216

__device__ __forceinline__ u16 f2bf(float x) {
  u32 u = __float_as_uint(x);
  u += 0x7fffu + ((u >> 16) & 1u);
  return (u16)(u >> 16);
}
__device__ __forceinline__ float bf2f(u16 h) {
  return __uint_as_float((u32)h << 16);
}

// ---------------------------------------------------------------------------
// fp32 -> bf16 hi (+ optional lo residual) elementwise
// ---------------------------------------------------------------------------
template <bool SPLIT>
__global__ __launch_bounds__(256) void k_split(const float* __restrict__ x,
                                               u16* __restrict__ hi,
                                               u16* __restrict__ lo, long n) {
  const long stride = (long)gridDim.x * 1024;
  for (long i = ((long)blockIdx.x * 256 + threadIdx.x) * 4; i < n;
       i += stride) {
    const float4 v = *(const float4*)(x + i);
    ushort4 h;
    h.x = f2bf(v.x);
    h.y = f2bf(v.y);
    h.z = f2bf(v.z);
    h.w = f2bf(v.w);
    *(ushort4*)(hi + i) = h;
    if constexpr (SPLIT) {
      ushort4 s;
      s.x = f2bf(v.x - bf2f(h.x));
      s.y = f2bf(v.y - bf2f(h.y));
      s.z = f2bf(v.z - bf2f(h.z));
      s.w = f2bf(v.w - bf2f(h.w));
      *(ushort4*)(lo + i) = s;
    }
  }
}

// ---------------------------------------------------------------------------
// MFMA GEMM building blocks. Tile 128x128, BK=32, 256 threads (4 waves, 2x2),
// each wave owns a 64x64 sub-tile = 4x4 fragments of 16x16x32 bf16 MFMA.
// LDS tiles are [row][32 bf16] (64 B rows); reads use chunk swizzle
// c' = c ^ ((r>>1)&3) (8 distinct bank slots per 8 rows -> ~2-way, free);
// staging keeps LDS dest LINEAR and applies the inverse swizzle to the
// per-lane GLOBAL source (rule: both-sides-or-neither with global_load_lds).
// ---------------------------------------------------------------------------
__device__ __forceinline__ void stage_tile(const u16* __restrict__ G, long ld,
                                           int row0, int k0, char* lds, int w,
                                           int l) {
#pragma unroll
  for (int i = 0; i < 2; ++i) {
    const int off = i * 4096 + w * 1024 + l * 16;
    const int r = off >> 6;
    const int cp = (off >> 4) & 3;
    const int c = cp ^ ((r >> 1) & 3);
    const u16* gp = G + (long)(row0 + r) * ld + k0 + c * 8;
    __builtin_amdgcn_global_load_lds((gptr_t)gp,
                                     (sptr_t)(lds + i * 4096 + w * 1024), 16,
                                     0, 0);
  }
}

__device__ __forceinline__ bf16x8 read_frag(const char* lds, int r, int ks) {
  const int cp = ks ^ ((r >> 1) & 3);
  return *(const bf16x8*)(lds + r * 64 + cp * 16);
}

// plain bf16 NT: C += A(MxK,row-major) * B(NxK,row-major)^T
__device__ __forceinline__ void core_plain(const u16* __restrict__ A, long lda,
                                           const u16* __restrict__ B, long ldb,
                                           int K, int bm, int bn, char* smem,
                                           f32x4 acc[4][4]) {
  const int tid = threadIdx.x, w = tid >> 6, l = tid & 63;
  const int wm = (w >> 1) * 64, wn = (w & 1) * 64;
  const int fr = l & 15, ks = l >> 4;
  char* As = smem;
  char* Bs = smem + 8192;
  for (int k0 = 0; k0 < K; k0 += BK) {
    stage_tile(A, lda, bm, k0, As, w, l);
    stage_tile(B, ldb, bn, k0, Bs, w, l);
    __syncthreads();
    bf16x8 af[4], bg[4];
#pragma unroll
    for (int i = 0; i < 4; ++i) {
      af[i] = read_frag(As, wm + i * 16 + fr, ks);
      bg[i] = read_frag(Bs, wn + i * 16 + fr, ks);
    }
#pragma unroll
    for (int mi = 0; mi < 4; ++mi)
#pragma unroll
      for (int ni = 0; ni < 4; ++ni)
        acc[mi][ni] = __builtin_amdgcn_mfma_f32_16x16x32_bf16(
            af[mi], bg[ni], acc[mi][ni], 0, 0, 0);
    __syncthreads();
  }
}

// split bf16 NT: A ~ Ah+Al, B ~ Bh+Bl; computes hh + hl + lh (3 MFMAs/pair)
__device__ __forceinline__ void core_split(
    const u16* __restrict__ Ah, const u16* __restrict__ Al, long lda,
    const u16* __restrict__ Bh, const u16* __restrict__ Bl, long ldb, int K,
    int bm, int bn, char* smem, f32x4 acc[4][4]) {
  const int tid = threadIdx.x, w = tid >> 6, l = tid & 63;
  const int wm = (w >> 1) * 64, wn = (w & 1) * 64;
  const int fr = l & 15, ks = l >> 4;
  char* Ash = smem;
  char* Bsh = smem + 8192;
  char* Asl = smem + 16384;
  char* Bsl = smem + 24576;
  for (int k0 = 0; k0 < K; k0 += BK) {
    stage_tile(Ah, lda, bm, k0, Ash, w, l);
    stage_tile(Bh, ldb, bn, k0, Bsh, w, l);
    stage_tile(Al, lda, bm, k0, Asl, w, l);
    stage_tile(Bl, ldb, bn, k0, Bsl, w, l);
    __syncthreads();
    bf16x8 ah[4], al[4], bh[4], bl[4];
#pragma unroll
    for (int i = 0; i < 4; ++i) {
      ah[i] = read_frag(Ash, wm + i * 16 + fr, ks);
      al[i] = read_frag(Asl, wm + i * 16 + fr, ks);
      bh[i] = read_frag(Bsh, wn + i * 16 + fr, ks);
      bl[i] = read_frag(Bsl, wn + i * 16 + fr, ks);
    }
#pragma unroll
    for (int mi = 0; mi < 4; ++mi)
#pragma unroll
      for (int ni = 0; ni < 4; ++ni) {
        acc[mi][ni] = __builtin_amdgcn_mfma_f32_16x16x32_bf16(
            ah[mi], bh[ni], acc[mi][ni], 0, 0, 0);
        acc[mi][ni] = __builtin_amdgcn_mfma_f32_16x16x32_bf16(
            ah[mi], bl[ni], acc[mi][ni], 0, 0, 0);
        acc[mi][ni] = __builtin_amdgcn_mfma_f32_16x16x32_bf16(
            al[mi], bh[ni], acc[mi][ni], 0, 0, 0);
      }
    __syncthreads();
  }
}

// C/D fragment coords: row = R0+j = bm+wm+mi*16+ks*4+j, col = bn+wn+ni*16+fr
#define EPI_PROLOG()                                        \
  const int tid = threadIdx.x, w = tid >> 6, l = tid & 63;  \
  const int wm = (w >> 1) * 64, wn = (w & 1) * 64;          \
  const int fr = l & 15, ks = l >> 4;

// ---------------------------------------------------------------------------
// qp/kp/vp projections (plain bf16), bf16 output
// ---------------------------------------------------------------------------
__global__ __launch_bounds__(256, 2) void k_proj_p(
    const u16* __restrict__ q_hi, const u16* __restrict__ k_hi,
    const u16* __restrict__ v_hi, const u16* __restrict__ Wq_h,
    const u16* __restrict__ Wk_h, const u16* __restrict__ Wv_h,
    u16* __restrict__ qp, u16* __restrict__ kp, u16* __restrict__ vp) {
  const u16 *A, *B;
  u16* C;
  switch (blockIdx.z) {
    case 0: A = q_hi; B = Wq_h; C = qp; break;
    case 1: A = k_hi; B = Wk_h; C = kp; break;
    default: A = v_hi; B = Wv_h; C = vp; break;
  }
  __shared__ __align__(16) char smem[16384];
  const int bm = blockIdx.y * 128, bn = blockIdx.x * 128;
  f32x4 acc[4][4] = {};
  core_plain(A, DD, B, DD, DD, bm, bn, smem, acc);
  EPI_PROLOG()
#pragma unroll
  for (int mi = 0; mi < 4; ++mi) {
    const int R0 = bm + wm + mi * 16 + ks * 4;
#pragma unroll
    for (int ni = 0; ni < 4; ++ni) {
      const int col = bn + wn + ni * 16 + fr;
#pragma unroll
      for (int j = 0; j < 4; ++j)
        C[(long)(R0 + j) * DD + col] = f2bf(acc[mi][ni][j]);
    }
  }
}

// ---------------------------------------------------------------------------
// qt0/kt0 projections (split), fp32 output
// ---------------------------------------------------------------------------
__global__ __launch_bounds__(256, 2) void k_proj_t(
    const u16* __restrict__ q_hi, const u16* __restrict__ q_lo,
    const u16* __restrict__ k_hi, const u16* __restrict__ k_lo,
    const u16* __restrict__ Wqt_h, const u16* __restrict__ Wqt_l,
    const u16* __restrict__ Wkt_h, const u16* __restrict__ Wkt_l,
    float* __restrict__ qt0f, float* __restrict__ kt0f) {
  const int sel = blockIdx.z;
  const u16* Ah = sel ? k_hi : q_hi;
  const u16* Al = sel ? k_lo : q_lo;
  const u16* Bh = sel ? Wkt_h : Wqt_h;
  const u16* Bl = sel ? Wkt_l : Wqt_l;
  float* C = sel ? kt0f : qt0f;
  __shared__ __align__(16) char smem[32768];
  const int bm = blockIdx.y * 128, bn = blockIdx.x * 128;
  f32x4 acc[4][4] = {};
  core_split(Ah, Al, DD, Bh, Bl, DD, DD, bm, bn, smem, acc);
  EPI_PROLOG()
#pragma unroll
  for (int mi = 0; mi < 4; ++mi) {
    const int R0 = bm + wm + mi * 16 + ks * 4;
#pragma unroll
    for (int ni = 0; ni < 4; ++ni) {
      const int col = bn + wn + ni * 16 + fr;
#pragma unroll
      for (int j = 0; j < 4; ++j)
        C[(long)(R0 + j) * DD + col] = acc[mi][ni][j];
    }
  }
}

// ---------------------------------------------------------------------------
// per-batch transpose + split: fp32 [1024][512] -> bf16 hi/lo [512][1024]
// z = b*2 + sel (0: qt0, 1: kt0)
// ---------------------------------------------------------------------------
__global__ __launch_bounds__(256) void k_tsplit(
    const float* __restrict__ qt0, const float* __restrict__ kt0,
    u16* __restrict__ qT_h, u16* __restrict__ qT_l, u16* __restrict__ kT_h,
    u16* __restrict__ kT_l) {
  const int b = blockIdx.z >> 1, sel = blockIdx.z & 1;
  const float* X = (sel ? kt0 : qt0) + (long)b * LL * DD;
  u16* Oh = (sel ? kT_h : qT_h) + (long)b * LL * DD;
  u16* Ol = (sel ? kT_l : qT_l) + (long)b * LL * DD;
  __shared__ float t[64][65];
  const int r0 = blockIdx.y * 64, c0 = blockIdx.x * 64;
  const int tid = threadIdx.x;
#pragma unroll
  for (int i = 0; i < 16; ++i) {
    const int idx = tid + i * 256;
    t[idx >> 6][idx & 63] = X[(long)(r0 + (idx >> 6)) * DD + c0 + (idx & 63)];
  }
  __syncthreads();
#pragma unroll
  for (int i = 0; i < 16; ++i) {
    const int idx = tid + i * 256;
    const int rr = idx >> 6, cc = idx & 63;
    const float x = t[cc][rr];
    const u16 h = f2bf(x);
    Oh[(long)(c0 + rr) * LL + r0 + cc] = h;
    Ol[(long)(c0 + rr) * LL + r0 + cc] = f2bf(x - bf2f(h));
  }
}

// per-batch bf16 transpose: [1024][512] -> [512][1024] (vp -> vpT)
__global__ __launch_bounds__(256) void k_tbf16(const u16* __restrict__ X,
                                               u16* __restrict__ O) {
  const int b = blockIdx.z;
  const u16* Xb = X + (long)b * LL * DD;
  u16* Ob = O + (long)b * LL * DD;
  __shared__ u16 t[64][68];
  const int r0 = blockIdx.y * 64, c0 = blockIdx.x * 64;
  const int tid = threadIdx.x;
#pragma unroll
  for (int i = 0; i < 16; ++i) {
    const int idx = tid + i * 256;
    t[idx >> 6][idx & 63] = Xb[(long)(r0 + (idx >> 6)) * DD + c0 + (idx & 63)];
  }
  __syncthreads();
#pragma unroll
  for (int i = 0; i < 16; ++i) {
    const int idx = tid + i * 256;
    const int rr = idx >> 6, cc = idx & 63;
    Ob[(long)(c0 + rr) * LL + r0 + cc] = t[cc][rr];
  }
}

// ---------------------------------------------------------------------------
// distance matmuls (split): qt = dist * qt0  -> split bf16 output
// z = b*2 + sel
// ---------------------------------------------------------------------------
__global__ __launch_bounds__(256, 2) void k_dist_g(
    const u16* __restrict__ dist_h, const u16* __restrict__ dist_l,
    const u16* __restrict__ qT_h, const u16* __restrict__ qT_l,
    const u16* __restrict__ kT_h, const u16* __restrict__ kT_l,
    u16* __restrict__ qt_h, u16* __restrict__ qt_l, u16* __restrict__ kt_h,
    u16* __restrict__ kt_l) {
  const int b = blockIdx.z >> 1, sel = blockIdx.z & 1;
  const u16* Ah = dist_h + (long)b * LL * LL;
  const u16* Al = dist_l + (long)b * LL * LL;
  const u16* Bh = (sel ? kT_h : qT_h) + (long)b * LL * DD;
  const u16* Bl = (sel ? kT_l : qT_l) + (long)b * LL * DD;
  u16* Oh = (sel ? kt_h : qt_h) + (long)b * LL * DD;
  u16* Ol = (sel ? kt_l : qt_l) + (long)b * LL * DD;
  __shared__ __align__(16) char smem[32768];
  const int bm = blockIdx.y * 128, bn = blockIdx.x * 128;
  f32x4 acc[4][4] = {};
  core_split(Ah, Al, LL, Bh, Bl, LL, LL, bm, bn, smem, acc);
  EPI_PROLOG()
#pragma unroll
  for (int mi = 0; mi < 4; ++mi) {
    const int R0 = bm + wm + mi * 16 + ks * 4;
#pragma unroll
    for (int ni = 0; ni < 4; ++ni) {
      const int col = bn + wn + ni * 16 + fr;
#pragma unroll
      for (int j = 0; j < 4; ++j) {
        const float x = acc[mi][ni][j];
        const u16 h = f2bf(x);
        Oh[(long)(R0 + j) * DD + col] = h;
        Ol[(long)(R0 + j) * DD + col] = f2bf(x - bf2f(h));
      }
    }
  }
}

// ---------------------------------------------------------------------------
// scores: split(qt,kt) + plain(qp,kp), then mask+tanh -> attn fp32 + bf16
// ---------------------------------------------------------------------------
__global__ __launch_bounds__(256, 2) void k_score(
    const u16* __restrict__ qp, const u16* __restrict__ kp,
    const u16* __restrict__ qt_h, const u16* __restrict__ qt_l,
    const u16* __restrict__ kt_h, const u16* __restrict__ kt_l,
    const int* __restrict__ lens, float* __restrict__ attnF,
    u16* __restrict__ attnB) {
  const int b = blockIdx.z;
  const long od = (long)b * LL * DD;
  __shared__ __align__(16) char smem[32768];
  const int bm = blockIdx.y * 128, bn = blockIdx.x * 128;
  f32x4 acc[4][4] = {};
  core_split(qt_h + od, qt_l + od, DD, kt_h + od, kt_l + od, DD, DD, bm, bn,
             smem, acc);
  core_plain(qp + od, DD, kp + od, DD, DD, bm, bn, smem, acc);
  const int len = lens[b];
  const float invt = 0.04419417382415922f;  // 1/sqrt(512)
  EPI_PROLOG()
#pragma unroll
  for (int mi = 0; mi < 4; ++mi) {
    const int R0 = bm + wm + mi * 16 + ks * 4;
#pragma unroll
    for (int ni = 0; ni < 4; ++ni) {
      const int col = bn + wn + ni * 16 + fr;
      const float m = (col < len) ? 1.0f : 0.0f;
#pragma unroll
      for (int j = 0; j < 4; ++j) {
        const float s = tanhf(acc[mi][ni][j] * invt * m) * m;
        const long idx = (long)b * LL * LL + (long)(R0 + j) * LL + col;
        attnF[idx] = s;
        attnB[idx] = f2bf(s);
      }
    }
  }
}

// ---------------------------------------------------------------------------
// PV: out0 = attn * vp   (plain, via vpT), bf16 output
// ---------------------------------------------------------------------------
__global__ __launch_bounds__(256, 2) void k_pv(const u16* __restrict__ attnB,
                                               const u16* __restrict__ vpT,
                                               u16* __restrict__ out0) {
  const int b = blockIdx.z;
  __shared__ __align__(16) char smem[16384];
  const int bm = blockIdx.y * 128, bn = blockIdx.x * 128;
  f32x4 acc[4][4] = {};
  core_plain(attnB + (long)b * LL * LL, LL, vpT + (long)b * LL * DD, LL, LL,
             bm, bn, smem, acc);
  u16* C = out0 + (long)b * LL * DD;
  EPI_PROLOG()
#pragma unroll
  for (int mi = 0; mi < 4; ++mi) {
    const int R0 = bm + wm + mi * 16 + ks * 4;
#pragma unroll
    for (int ni = 0; ni < 4; ++ni) {
      const int col = bn + wn + ni * 16 + fr;
#pragma unroll
      for (int j = 0; j < 4; ++j)
        C[(long)(R0 + j) * DD + col] = f2bf(acc[mi][ni][j]);
    }
  }
}

// ---------------------------------------------------------------------------
// FC + residual: out1 = out0 * Wfc^T + q   (plain), fp32 output
// ---------------------------------------------------------------------------
__global__ __launch_bounds__(256, 2) void k_fc(const u16* __restrict__ out0,
                                               const u16* __restrict__ Wfc_h,
                                               const float* __restrict__ q,
                                               float* __restrict__ out1) {
  __shared__ __align__(16) char smem[16384];
  const int bm = blockIdx.y * 128, bn = blockIdx.x * 128;
  f32x4 acc[4][4] = {};
  core_plain(out0, DD, Wfc_h, DD, DD, bm, bn, smem, acc);
  EPI_PROLOG()
#pragma unroll
  for (int mi = 0; mi < 4; ++mi) {
    const int R0 = bm + wm + mi * 16 + ks * 4;
#pragma unroll
    for (int ni = 0; ni < 4; ++ni) {
      const int col = bn + wn + ni * 16 + fr;
#pragma unroll
      for (int j = 0; j < 4; ++j) {
        const long r = (long)(R0 + j) * DD + col;
        out1[r] = acc[mi][ni][j] + q[r];
      }
    }
  }
}

// ---------------------------------------------------------------------------
// LayerNorm over last dim (512)
// ---------------------------------------------------------------------------
__global__ __launch_bounds__(256) void k_ln(const float* __restrict__ x,
                                            const float* __restrict__ gamma,
                                            const float* __restrict__ beta,
                                            float* __restrict__ y) {
  const int r = blockIdx.x;
  const float* xr = x + (long)r * DD;
  const int t = threadIdx.x;
  const float x0 = xr[t], x1 = xr[t + 256];
  float s1 = x0 + x1;
  float s2 = x0 * x0 + x1 * x1;
#pragma unroll
  for (int off = 32; off; off >>= 1) {
    s1 += __shfl_down(s1, off);
    s2 += __shfl_down(s2, off);
  }
  __shared__ float r1[4], r2[4];
  __shared__ float smu, srs;
  if ((t & 63) == 0) {
    r1[t >> 6] = s1;
    r2[t >> 6] = s2;
  }
  __syncthreads();
  if (t == 0) {
    const float t1 = r1[0] + r1[1] + r1[2] + r1[3];
    const float t2 = r2[0] + r2[1] + r2[2] + r2[3];
    const float mu = t1 / (float)DD;
    smu = mu;
    srs = rsqrtf(t2 / (float)DD - mu * mu + 1e-6f);
  }
  __syncthreads();
  const float mu = smu, rs = srs;
  y[(long)r * DD + t] = (x0 - mu) * rs * gamma[t] + beta[t];
  y[(long)r * DD + t + 256] = (x1 - mu) * rs * gamma[t + 256] + beta[t + 256];
}

// ---------------------------------------------------------------------------
extern "C" void kernel_launch(void* const* d_in, const int* in_sizes, int n_in,
                              void* d_out, int out_size, void* d_ws,
                              size_t ws_size, hipStream_t stream) {
  const float* q = (const float*)d_in[0];
  const float* k = (const float*)d_in[1];
  const float* v = (const float*)d_in[2];
  const int* lens = (const int*)d_in[3];
  const float* dist = (const float*)d_in[4];
  const float* Wq = (const float*)d_in[5];
  const float* Wk = (const float*)d_in[6];
  const float* Wv = (const float*)d_in[7];
  const float* Wqt = (const float*)d_in[8];
  const float* Wkt = (const float*)d_in[9];
  const float* Wfc = (const float*)d_in[10];
  const float* gamma = (const float*)d_in[11];
  const float* beta = (const float*)d_in[12];

  char* W = (char*)d_ws;
  const size_t SB = 16777216;  // bytes of one bf16 [16384][512] buffer
  u16* q_hi = (u16*)(W + 0 * SB);    // reused later as qt_h
  u16* q_lo = (u16*)(W + 1 * SB);    // reused later as qt_l
  u16* k_hi = (u16*)(W + 2 * SB);    // reused later as kt_h
  u16* k_lo = (u16*)(W + 3 * SB);    // reused later as kt_l
  u16* v_hi = (u16*)(W + 4 * SB);    // reused later as vpT
  u16* dist_h = (u16*)(W + 5 * SB);  // 2SB; reused later as attnB
  u16* dist_l = (u16*)(W + 7 * SB);  // 2SB
  u16* qp_bf = (u16*)(W + 9 * SB);   // reused later as out0
  u16* kp_bf = (u16*)(W + 10 * SB);
  u16* vp_bf = (u16*)(W + 11 * SB);
  float* qt0f = (float*)(W + 12 * SB);  // 2SB; reused later as out1
  float* kt0f = (float*)(W + 14 * SB);  // 2SB
  u16* qT_h = (u16*)(W + 16 * SB);
  u16* qT_l = (u16*)(W + 17 * SB);
  u16* kT_h = (u16*)(W + 18 * SB);
  u16* kT_l = (u16*)(W + 19 * SB);
  char* WB = W + 20 * SB;
  const size_t WS = 524288;
  u16* Wq_h = (u16*)(WB + 0 * WS);
  u16* Wk_h = (u16*)(WB + 1 * WS);
  u16* Wv_h = (u16*)(WB + 2 * WS);
  u16* Wfc_h = (u16*)(WB + 3 * WS);
  u16* Wqt_h = (u16*)(WB + 4 * WS);
  u16* Wqt_l = (u16*)(WB + 5 * WS);
  u16* Wkt_h = (u16*)(WB + 6 * WS);
  u16* Wkt_l = (u16*)(WB + 7 * WS);
  // aliases (lifetimes disjoint, stream-ordered)
  u16* qt_h = q_hi;
  u16* qt_l = q_lo;
  u16* kt_h = k_hi;
  u16* kt_l = k_lo;
  u16* vpT = v_hi;
  u16* attnB = dist_h;
  u16* out0 = qp_bf;
  float* out1 = qt0f;

  float* outO = (float*)d_out;
  float* attnF = outO + NLD;

  dim3 blk(256);
  k_split<true><<<4096, blk, 0, stream>>>(q, q_hi, q_lo, NLD);
  k_split<true><<<4096, blk, 0, stream>>>(k, k_hi, k_lo, NLD);
  k_split<false><<<4096, blk, 0, stream>>>(v, v_hi, nullptr, NLD);
  k_split<true><<<4096, blk, 0, stream>>>(dist, dist_h, dist_l, NLL);
  k_split<false><<<256, blk, 0, stream>>>(Wq, Wq_h, nullptr, 262144);
  k_split<false><<<256, blk, 0, stream>>>(Wk, Wk_h, nullptr, 262144);
  k_split<false><<<256, blk, 0, stream>>>(Wv, Wv_h, nullptr, 262144);
  k_split<false><<<256, blk, 0, stream>>>(Wfc, Wfc_h, nullptr, 262144);
  k_split<true><<<256, blk, 0, stream>>>(Wqt, Wqt_h, Wqt_l, 262144);
  k_split<true><<<256, blk, 0, stream>>>(Wkt, Wkt_h, Wkt_l, 262144);

  k_proj_p<<<dim3(4, 128, 3), blk, 0, stream>>>(q_hi, k_hi, v_hi, Wq_h, Wk_h,
                                                Wv_h, qp_bf, kp_bf, vp_bf);
  k_proj_t<<<dim3(4, 128, 2), blk, 0, stream>>>(
      q_hi, q_lo, k_hi, k_lo, Wqt_h, Wqt_l, Wkt_h, Wkt_l, qt0f, kt0f);
  k_tsplit<<<dim3(8, 16, 32), blk, 0, stream>>>(qt0f, kt0f, qT_h, qT_l, kT_h,
                                                kT_l);
  k_tbf16<<<dim3(8, 16, 16), blk, 0, stream>>>(vp_bf, vpT);
  k_dist_g<<<dim3(4, 8, 32), blk, 0, stream>>>(dist_h, dist_l, qT_h, qT_l,
                                               kT_h, kT_l, qt_h, qt_l, kt_h,
                                               kt_l);
  k_score<<<dim3(8, 8, 16), blk, 0, stream>>>(qp_bf, kp_bf, qt_h, qt_l, kt_h,
                                              kt_l, lens, attnF, attnB);
  k_pv<<<dim3(4, 8, 16), blk, 0, stream>>>(attnB, vpT, out0);
  k_fc<<<dim3(4, 128, 1), blk, 0, stream>>>(out0, Wfc_h, q, out1);
  k_ln<<<NB * LL, blk, 0, stream>>>(out1, gamma, beta, outO);
}